// Round 5
// baseline (544.626 us; speedup 1.0000x reference)
//
#include <hip/hip_runtime.h>
#include <math.h>

#define WINSZ  8
#define SHIFTV 4
#define DIM    96
#define HEADS  6
#define HEAD_D 16
#define MLP_H  384
#define HH     512
#define WWID   512
#define HWSZ   (HH*WWID)
#define NTOK   64
#define EPSV   1e-5f
#define XP     97
#define QP     17
#define BFP    120

#define L2E    1.44269504088896f
#define QSC    0.360673760222f   /* 0.25 * log2(e) */

// ws layout (in shorts)
#define OFF_W1   0        /* 36864: fc1 bf16 */
#define OFF_W2   36864    /* 36864: fc2 bf16 */
#define OFF_QKV  73728    /* 27648: qkv_w bf16 */
#define OFF_PROJ 101376   /*  9216: proj_w bf16 */
#define OFF_BIAS 110592   /* 98304: bias+mask table bf16 [4][6][64][64], pre-scaled by log2e */
#define WS_FULL  208896
#define WS_MLP   73728

// LDS pitches
#define QKP 104   /* shorts, qb/kb2/lnb2/hid rows (16B-aligned b128) */
#define VTP 72    /* shorts, vT rows */
#define X1P 100   /* floats, parked-x1 rows (400B, 16B-aligned f4v) */

// LDS map (40448 B total -> 4 blocks/CU):
//  phase A: qb@0 (13312) | kb2@13312 (13312) | vT@26624 (13824, ends 40448)
//  post-B2: x1p@13312 (float [64][100] = 25600, ends 38912) over kb2/vT
//  qb region is wave-private-row THROUGHOUT: aob/lnb2/hid all overlay it.
//  Only 2 barriers per block: B1 (k/v ready), B2 (kb2/vT free for x1p).
#define SMEM_SZ 40448

typedef __attribute__((ext_vector_type(2))) short  s2v;
typedef __attribute__((ext_vector_type(4))) short  s4v;
typedef __attribute__((ext_vector_type(8))) short  s8v;
typedef __attribute__((ext_vector_type(4))) float  f4v;
typedef __attribute__((ext_vector_type(4))) unsigned short u4v;

__device__ __forceinline__ unsigned short f2bf(float v) {
    union { float f; unsigned u; } c; c.f = v;
    unsigned r = c.u + 0x7fffu + ((c.u >> 16) & 1u);
    return (unsigned short)(r >> 16);
}
__device__ __forceinline__ float bf2f(unsigned short u) {
    union { unsigned u; float f; } c; c.u = ((unsigned)u) << 16; return c.f;
}
// packed f32x2 -> bf16x2 (RNE), 1 VALU instead of 6
__device__ __forceinline__ unsigned pk2(float a, float b) {
    unsigned r;
    asm("v_cvt_pk_bf16_f32 %0, %1, %2" : "=v"(r) : "v"(a), "v"(b));
    return r;
}
__device__ __forceinline__ s4v pk4(f4v v) {
    union { unsigned u[2]; s4v s; } o;
    o.u[0] = pk2(v[0], v[1]);
    o.u[1] = pk2(v[2], v[3]);
    return o.s;
}
__device__ __forceinline__ float fexp2(float x) {
#if __has_builtin(__builtin_amdgcn_exp2f)
    return __builtin_amdgcn_exp2f(x);
#else
    return exp2f(x);
#endif
}
__device__ __forceinline__ unsigned long long shfl64(unsigned long long v, int src) {
    union { unsigned long long q; int i[2]; } c; c.q = v;
    c.i[0] = __shfl(c.i[0], src);
    c.i[1] = __shfl(c.i[1], src);
    return c.q;
}
// tanh-form gelu in exp2 domain.
__device__ __forceinline__ float fast_gelu(float h) {
    float h2 = h*h;
    float u  = fmaf(0.044715f, h2, 1.0f);
    float e  = fexp2(-2.3022082f * h * u);   /* -1.5957691*log2e */
    return h * __builtin_amdgcn_rcpf(1.0f + e);
}

// ---------------------------------------------------------------------------
// conv_all: weights fp32->bf16 + rel-pos-bias/mask table (pre-scaled by
// log2e for the exp2-domain softmax) into ws.
// ---------------------------------------------------------------------------
__global__ __launch_bounds__(256) void conv_all(
    const float* __restrict__ qkvw, const float* __restrict__ projw,
    const float* __restrict__ f1w,  const float* __restrict__ f2w,
    const float* __restrict__ rpb,  short* __restrict__ ws)
{
    int i = (blockIdx.x*256 + threadIdx.x)*4;
    if (i < 110592) {
        const float* src; int off;
        if (i < 36864)       { src = f1w;  off = i;          }
        else if (i < 73728)  { src = f2w;  off = i - 36864;  }
        else if (i < 101376) { src = qkvw; off = i - 73728;  }
        else                 { src = projw; off = i - 101376; }
        f4v v = *(const f4v*)&src[off];
        s4v o;
        #pragma unroll
        for (int j = 0; j < 4; ++j) o[j] = (short)f2bf(v[j]);
        *(s4v*)&ws[i] = o;
    } else if (i < WS_FULL) {
        int idx = i - 110592;
        int tb = idx / 24576;
        int rm = idx - tb*24576;
        int hd = rm >> 12;
        int rc = rm & 4095;
        int r = rc >> 6, c0 = rc & 63;
        int rti = r>>3, rtj = r&7;
        int bh = tb>>1, bw = tb&1;
        int rhr = bh ? (rti<4?1:2) : 0;
        int rwr = bw ? (rtj<4?1:2) : 0;
        s4v o;
        #pragma unroll
        for (int j = 0; j < 4; ++j) {
            int c = c0 + j;
            int cti = c>>3, ctj = c&7;
            int rel = (rti-cti+7)*15 + (rtj-ctj+7);
            float b = rpb[rel*HEADS + hd];
            int rhc = bh ? (cti<4?1:2) : 0;
            int rwc = bw ? (ctj<4?1:2) : 0;
            if (rhr != rhc || rwr != rwc) b -= 100.f;
            o[j] = (short)f2bf(b * L2E);
        }
        *(s4v*)&ws[OFF_BIAS + idx] = o;
    }
}

// ---------------------------------------------------------------------------
// fused_kernel: one block per window, TWO barriers total.
// LN1(in-reg) -> QKV (explicit 2-buffer register weight pipeline) -> B1 ->
// heads (no-max exp2 softmax, out in-place over Q) -> B2 -> proj -> LN2 ->
// park x1 in freed LDS -> MLP (16 barrier-free phases, register-direct
// double-buffered weights; hid rows wave-private) -> residual add -> store.
// ---------------------------------------------------------------------------
__global__ __launch_bounds__(256,4) void fused_kernel(
    const float* __restrict__ x,
    const float* __restrict__ n1w, const float* __restrict__ n1b,
    const float* __restrict__ qkvb, const float* __restrict__ projb,
    const float* __restrict__ n2w, const float* __restrict__ n2b,
    const float* __restrict__ f1b, const float* __restrict__ f2b,
    const short* __restrict__ wqkv, const short* __restrict__ wproj,
    const short* __restrict__ w1b, const short* __restrict__ w2b,
    const short* __restrict__ btab,
    float* __restrict__ out)
{
    __shared__ __align__(16) char smem[SMEM_SZ];
    short* qb   = (short*)smem;              // [64][104]; aob/lnb2/hid overlay
    short* kb2  = (short*)(smem + 13312);    // [64][104]
    short* vT   = (short*)(smem + 26624);    // [96][72] (ends 40448)
    short* aob  = qb;
    short* lnb2 = qb;
    short* hid  = qb;
    float* x1p  = (float*)(smem + 13312);    // [64][100] f32, post-B2

    const int tid  = threadIdx.x;
    const int wv   = tid >> 6, lane = tid & 63;
    const int col  = lane & 15, kq = lane >> 4;
    const int trow = wv*16 + col;
    const int mrow = wv*16;

    // ---- block -> window swizzle (4 w-adjacent windows per XCD slot) ----
    int bid = blockIdx.x;
    int wl = (bid & 7)*512 + ((bid >> 5) << 2) + ((bid >> 3) & 3);
    const int wi = wl >> 6, wj = wl & 63;

    // this thread's token position (token = trow, wave-private)
    const int ti = trow>>3, tj = trow&7;
    const int hpos = (wi*8 + ti + SHIFTV) & (HH-1);
    const int wpos = (wj*8 + tj + SHIFTV) & (WWID-1);
    const int p = hpos*WWID + wpos;

    // ---- LN1 fully in registers ----
    s8v bfr[3];
    {
        float v[24], s1 = 0.f, s2 = 0.f;
        #pragma unroll
        for (int kb = 0; kb < 3; ++kb)
            #pragma unroll
            for (int j = 0; j < 8; ++j) {
                float vv = x[(kb*32 + kq*8 + j)*HWSZ + p];
                v[kb*8+j] = vv; s1 += vv; s2 += vv*vv;
            }
        s1 += __shfl_xor(s1, 16); s2 += __shfl_xor(s2, 16);
        s1 += __shfl_xor(s1, 32); s2 += __shfl_xor(s2, 32);
        float mu = s1*(1.f/96.f);
        float rs = rsqrtf(s2*(1.f/96.f) - mu*mu + EPSV);
        #pragma unroll
        for (int kb = 0; kb < 3; ++kb) {
            f4v wA = *(const f4v*)&n1w[kb*32 + kq*8];
            f4v wB = *(const f4v*)&n1w[kb*32 + kq*8 + 4];
            f4v bA = *(const f4v*)&n1b[kb*32 + kq*8];
            f4v bB = *(const f4v*)&n1b[kb*32 + kq*8 + 4];
            float a[8];
            #pragma unroll
            for (int j = 0; j < 4; ++j) {
                a[j]   = (v[kb*8+j]  -mu)*rs*wA[j] + bA[j];
                a[4+j] = (v[kb*8+4+j]-mu)*rs*wB[j] + bB[j];
            }
            union { unsigned u[4]; s8v s; } o;
            #pragma unroll
            for (int j = 0; j < 4; ++j) o.u[j] = pk2(a[2*j], a[2*j+1]);
            bfr[kb] = o.s;
        }
    }

    // ---- hoist shortcut reads (consumed in proj) ----
    float shc[24];
    #pragma unroll
    for (int mt = 0; mt < 6; ++mt)
        #pragma unroll
        for (int i = 0; i < 4; ++i)
            shc[mt*4+i] = x[(mt*16 + kq*4 + i)*HWSZ + p];

    const s8v zfrag = {0,0,0,0,0,0,0,0};

    // ---- QKV with explicit double-buffered weight pipeline ----
    {
        auto qkv_pre = [&](int g, s8v (&w)[9]) {
            #pragma unroll
            for (int m = 0; m < 3; ++m)
                #pragma unroll
                for (int kb = 0; kb < 3; ++kb)
                    w[m*3+kb] = *(const s8v*)&wqkv[((g*3+m)*16+col)*96 + kb*32 + kq*8];
        };
        auto qkv_cmp = [&](int g, const s8v (&w)[9]) {
            #pragma unroll
            for (int m = 0; m < 3; ++m) {
                int mt = g*3 + m;
                f4v acc = {0.f,0.f,0.f,0.f};
                #pragma unroll
                for (int kb = 0; kb < 3; ++kb)
                    acc = __builtin_amdgcn_mfma_f32_16x16x32_bf16(w[m*3+kb], bfr[kb], acc, 0,0,0);
                int od0 = mt*16 + kq*4;
                f4v bia = *(const f4v*)&qkvb[od0];
                if (mt < 6) {
                    f4v t;
                    #pragma unroll
                    for (int i = 0; i < 4; ++i) t[i] = (acc[i]+bia[i])*QSC;
                    *(s4v*)&qb[trow*QKP + od0] = pk4(t);
                } else if (mt < 12) {
                    f4v t;
                    #pragma unroll
                    for (int i = 0; i < 4; ++i) t[i] = acc[i]+bia[i];
                    *(s4v*)&kb2[trow*QKP + od0 - 96] = pk4(t);
                } else {
                    int d0 = od0 - 192;
                    f4v t;
                    #pragma unroll
                    for (int i = 0; i < 4; ++i) t[i] = acc[i]+bia[i];
                    s4v o = pk4(t);
                    #pragma unroll
                    for (int i = 0; i < 4; ++i)
                        vT[(d0+i)*VTP + trow] = o[i];
                }
            }
        };
        s8v qwA[9], qwB[9];
        qkv_pre(0, qwA);
        #pragma unroll
        for (int gp = 0; gp < 3; ++gp) {
            qkv_pre(2*gp+1, qwB);
            qkv_cmp(2*gp,   qwA);
            if (gp < 2) qkv_pre(2*gp+2, qwA);
            qkv_cmp(2*gp+1, qwB);
        }
    }
    __syncthreads();   // B1: k/v (cross-wave) ready

    // ---- heads: S^T = K @ Q^T (log2 domain), no-max exp2 softmax, PV via
    // register shuffles. Bias rows rotate-prefetched one head ahead. ----
    const int tb = ((wi==63)?2:0) | ((wj==63)?1:0);
    u4v bt[4];
    {
        const short* gb = btab + ((tb*6+0)<<12) + (trow<<6);
        #pragma unroll
        for (int mt = 0; mt < 4; ++mt) bt[mt] = *(const u4v*)&gb[mt*16 + kq*4];
    }
    for (int hd = 0; hd < 6; ++hd) {
        u4v btn[4];
        if (hd < 5) {
            const short* gb = btab + ((tb*6+hd+1)<<12) + (trow<<6);
            #pragma unroll
            for (int mt = 0; mt < 4; ++mt) btn[mt] = *(const u4v*)&gb[mt*16 + kq*4];
        }
        s8v bq = zfrag;
        if (kq < 2) bq = *(const s8v*)&qb[trow*QKP + hd*16 + kq*8];
        f4v st[4];
        #pragma unroll
        for (int mt = 0; mt < 4; ++mt) {
            s8v a = zfrag;
            if (kq < 2) a = *(const s8v*)&kb2[(mt*16+col)*QKP + hd*16 + kq*8];
            f4v z = {0.f,0.f,0.f,0.f};
            st[mt] = __builtin_amdgcn_mfma_f32_16x16x32_bf16(a, bq, z, 0,0,0);
        }
        float pe[16];
        #pragma unroll
        for (int mt = 0; mt < 4; ++mt)
            #pragma unroll
            for (int i = 0; i < 4; ++i)
                pe[mt*4+i] = fexp2(st[mt][i] + bf2f(bt[mt][i]));
        float s8r[8];
        #pragma unroll
        for (int j = 0; j < 8; ++j) s8r[j] = pe[2*j] + pe[2*j+1];
        #pragma unroll
        for (int j = 0; j < 4; ++j) s8r[j] += s8r[j+4];
        float sum = (s8r[0]+s8r[2]) + (s8r[1]+s8r[3]);
        sum += __shfl_xor(sum, 16);
        sum += __shfl_xor(sum, 32);
        unsigned long long p64[4];
        #pragma unroll
        for (int mt = 0; mt < 4; ++mt) {
            union { unsigned u[2]; unsigned long long q; } pq;
            pq.u[0] = pk2(pe[mt*4+0], pe[mt*4+1]);
            pq.u[1] = pk2(pe[mt*4+2], pe[mt*4+3]);
            p64[mt] = pq.q;
        }
        const int s0 = col + ((kq & 1) << 5);
        const int sel = kq >> 1;
        f4v g = {0.f,0.f,0.f,0.f};
        #pragma unroll
        for (int c = 0; c < 2; ++c) {
            unsigned long long t0 = shfl64(p64[2*c],   s0);
            unsigned long long t1 = shfl64(p64[2*c+1], s0);
            unsigned long long lo = sel ? t1 : t0;
            unsigned long long u0 = shfl64(p64[2*c],   s0+16);
            unsigned long long u1 = shfl64(p64[2*c+1], s0+16);
            unsigned long long hi = sel ? u1 : u0;
            union { unsigned long long q[2]; s8v v; } bb;
            bb.q[0] = lo; bb.q[1] = hi;
            s8v a = *(const s8v*)&vT[(hd*16+col)*VTP + c*32 + kq*8];
            g = __builtin_amdgcn_mfma_f32_16x16x32_bf16(a, bb.v, g, 0,0,0);
        }
        float linv = __builtin_amdgcn_rcpf(sum);
        f4v gl;
        #pragma unroll
        for (int i = 0; i < 4; ++i) gl[i] = g[i]*linv;
        *(s4v*)&aob[trow*QKP + hd*16 + kq*4] = pk4(gl);
        #pragma unroll
        for (int mt = 0; mt < 4; ++mt) bt[mt] = btn[mt];
    }
    __syncthreads();   // B2: all waves done with kb2/vT (x1p overwrites next)

    // ---- proj: C^T = W_proj @ ao^T ; x1 = shortcut + proj-out in regs ----
    float x1r[24];
    {
        s8v bfr2[3];
        #pragma unroll
        for (int kb = 0; kb < 3; ++kb)
            bfr2[kb] = *(const s8v*)&aob[trow*QKP + kb*32 + kq*8];
        s8v pw[18];
        #pragma unroll
        for (int mt = 0; mt < 6; ++mt)
            #pragma unroll
            for (int kb = 0; kb < 3; ++kb)
                pw[mt*3+kb] = *(const s8v*)&wproj[(mt*16+col)*96 + kb*32 + kq*8];
        #pragma unroll
        for (int mt = 0; mt < 6; ++mt) {
            f4v acc = {0.f,0.f,0.f,0.f};
            #pragma unroll
            for (int kb = 0; kb < 3; ++kb)
                acc = __builtin_amdgcn_mfma_f32_16x16x32_bf16(pw[mt*3+kb], bfr2[kb], acc, 0,0,0);
            int c0 = mt*16 + kq*4;
            f4v pb4 = *(const f4v*)&projb[c0];
            #pragma unroll
            for (int i = 0; i < 4; ++i)
                x1r[mt*4+i] = shc[mt*4+i] + acc[i] + pb4[i];
        }
    }

    // ---- LN2 in registers -> lnb2 (over qb, wave-private rows) ----
    {
        float s1 = 0.f, s2 = 0.f;
        #pragma unroll
        for (int j = 0; j < 24; ++j) { s1 += x1r[j]; s2 += x1r[j]*x1r[j]; }
        s1 += __shfl_xor(s1, 16); s2 += __shfl_xor(s2, 16);
        s1 += __shfl_xor(s1, 32); s2 += __shfl_xor(s2, 32);
        float mu = s1*(1.f/96.f);
        float rs = rsqrtf(s2*(1.f/96.f) - mu*mu + EPSV);
        #pragma unroll
        for (int mt = 0; mt < 6; ++mt) {
            int c0 = mt*16 + kq*4;
            f4v w4 = *(const f4v*)&n2w[c0];
            f4v b4 = *(const f4v*)&n2b[c0];
            f4v t;
            #pragma unroll
            for (int i = 0; i < 4; ++i)
                t[i] = (x1r[mt*4+i]-mu)*rs*w4[i] + b4[i];
            *(s4v*)&lnb2[trow*QKP + c0] = pk4(t);
        }
    }
    __threadfence_block();

    // ---- park x1 into freed kb2/vT region (frees 24 VGPR for MLP) ----
    #pragma unroll
    for (int mt = 0; mt < 6; ++mt) {
        f4v t;
        #pragma unroll
        for (int i = 0; i < 4; ++i) t[i] = x1r[mt*4+i];
        *(f4v*)&x1p[trow*X1P + mt*16 + kq*4] = t;
    }

    // ---- MLP: 16 barrier-free phases {fc1a,fc1b,fc2a,fc2b} x 4ch.
    // Register-direct weights, explicit double buffer: prefetch phase p+1
    // while computing phase p. hid rows wave-private; LDS order within a
    // wave is hardware-guaranteed, fences stop compiler reordering. ----
    s8v a1[3], a2[3];
    #pragma unroll
    for (int kb = 0; kb < 3; ++kb)
        a1[kb] = *(const s8v*)&lnb2[(mrow+col)*QKP + kb*32 + kq*8];
    __threadfence_block();   // a1 reads ordered before hid writes

    f4v acc2[6];
    #pragma unroll
    for (int n = 0; n < 6; ++n) acc2[n] = (f4v){0.f,0.f,0.f,0.f};

    auto mlp_pre = [&](int ph, s8v (&w)[9]) {
        const int ch = ph >> 2, q = ph & 3;
        #pragma unroll
        for (int nl = 0; nl < 3; ++nl)
            #pragma unroll
            for (int kb = 0; kb < 3; ++kb) {
                if (q < 2)
                    w[nl*3+kb] = *(const s8v*)&w1b[(ch*96 + q*48 + nl*16 + col)*96 + kb*32 + kq*8];
                else
                    w[nl*3+kb] = *(const s8v*)&w2b[((q-2)*48 + nl*16 + col)*MLP_H + ch*96 + kb*32 + kq*8];
            }
    };
    auto mlp_phase = [&](int ph, const s8v (&w)[9]) {
        const int ch = ph >> 2, q = ph & 3;
        if (q < 2) {
            #pragma unroll
            for (int nl = 0; nl < 3; ++nl) {
                f4v acc = (f4v){0.f,0.f,0.f,0.f};
                #pragma unroll
                for (int kb = 0; kb < 3; ++kb)
                    acc = __builtin_amdgcn_mfma_f32_16x16x32_bf16(a1[kb], w[nl*3+kb], acc, 0,0,0);
                int cch = q*48 + nl*16 + col;
                float bias = f1b[ch*96 + cch];
                f4v t;
                #pragma unroll
                for (int i = 0; i < 4; ++i) t[i] = fast_gelu(acc[i]+bias);
                s4v o = pk4(t);
                #pragma unroll
                for (int i = 0; i < 4; ++i)
                    hid[(mrow + kq*4 + i)*QKP + cch] = o[i];
            }
            if (q == 1) {
                __threadfence_block();
                #pragma unroll
                for (int kb = 0; kb < 3; ++kb)
                    a2[kb] = *(const s8v*)&hid[(mrow+col)*QKP + kb*32 + kq*8];
            }
        } else {
            #pragma unroll
            for (int nl = 0; nl < 3; ++nl) {
                int nt = (q-2)*3 + nl;
                #pragma unroll
                for (int kb = 0; kb < 3; ++kb)
                    acc2[nt] = __builtin_amdgcn_mfma_f32_16x16x32_bf16(a2[kb], w[nl*3+kb], acc2[nt], 0,0,0);
            }
        }
    };

    {
        s8v wA[9], wB[9];
        mlp_pre(0, wA);
        #pragma unroll
        for (int pp = 0; pp < 8; ++pp) {
            mlp_pre(2*pp+1, wB);
            mlp_phase(2*pp, wA);
            if (pp < 7) mlp_pre(2*pp+2, wA);
            mlp_phase(2*pp+1, wB);
        }
    }

    // ---- residual add into parked x1 (wave-private rows), then store ----
    __threadfence_block();
    #pragma unroll
    for (int nt = 0; nt < 6; ++nt) {
        int c = nt*16 + col;
        float bias = f2b[c];
        #pragma unroll
        for (int i = 0; i < 4; ++i) {
            int t = mrow + kq*4 + i;
            x1p[t*X1P + c] += acc2[nt][i] + bias;
        }
    }
    __threadfence_block();
    {
        int tt = mrow + col;
        int tti = tt>>3, ttj = tt&7;
        int pp = ((wi*8 + tti + SHIFTV) & (HH-1))*WWID + ((wj*8 + ttj + SHIFTV) & (WWID-1));
        #pragma unroll
        for (int it = 0; it < 24; ++it) {
            int c = it*4 + kq;
            out[c*HWSZ + pp] = x1p[tt*X1P + c];
        }
    }
}

// ---------------------------------------------------------------------------
// Fallback fp32 attention + bf16 MLP if ws too small.
// ---------------------------------------------------------------------------
__global__ __launch_bounds__(256) void attn_kernel(
    const float* __restrict__ x,
    const float* __restrict__ n1w, const float* __restrict__ n1b,
    const float* __restrict__ qkvw, const float* __restrict__ qkvb,
    const float* __restrict__ rpb,
    const float* __restrict__ projw, const float* __restrict__ projb,
    float* __restrict__ out)
{
    __shared__ float xn[NTOK*XP];
    __shared__ float ao[NTOK*XP];
    __shared__ float qh[NTOK*QP];
    __shared__ float kh[NTOK*QP];
    __shared__ float vh[NTOK*QP];
    __shared__ int   srid[NTOK];
    __shared__ int   spos[NTOK];

    const int tid = threadIdx.x;
    const int blk = blockIdx.x;
    const int wi = blk >> 6, wj = blk & 63;

    {
        int t  = tid >> 2;
        int j4 = tid & 3;
        int ti = t >> 3, tj = t & 7;
        int a = wi*WINSZ + ti;
        int bcol = wj*WINSZ + tj;
        int h = (a + SHIFTV) & (HH-1);
        int w = (bcol + SHIFTV) & (WWID-1);
        int p = h*WWID + w;
        if (j4 == 0) {
            spos[t] = p;
            int rh = (a < HH-WINSZ) ? 0 : (a < HH-SHIFTV ? 1 : 2);
            int rw = (bcol < WWID-WINSZ) ? 0 : (bcol < WWID-SHIFTV ? 1 : 2);
            srid[t] = rh*3 + rw;
        }
        float xv[24];
        float s1 = 0.f, s2 = 0.f;
        int c0 = j4*24;
        #pragma unroll
        for (int i = 0; i < 24; ++i) {
            float v = x[(c0+i)*HWSZ + p];
            xv[i] = v; s1 += v; s2 += v*v;
        }
        s1 += __shfl_xor(s1,1); s2 += __shfl_xor(s2,1);
        s1 += __shfl_xor(s1,2); s2 += __shfl_xor(s2,2);
        float mu  = s1 * (1.f/96.f);
        float var = s2 * (1.f/96.f) - mu*mu;
        float rs  = rsqrtf(var + EPSV);
        #pragma unroll
        for (int i = 0; i < 24; ++i) {
            int c = c0 + i;
            xn[t*XP + c] = (xv[i]-mu)*rs*n1w[c] + n1b[c];
        }
    }
    __syncthreads();

    const int wv   = tid >> 6;
    const int lane = tid & 63;
    const int r    = tid >> 2;
    const int g    = tid & 3;
    const int rti  = r >> 3, rtj = r & 7;

    for (int hd = 0; hd < HEADS; ++hd) {
        for (int it = 0; it < 12; ++it) {
            int ol = it*4 + wv;
            int s = ol >> 4, d = ol & 15;
            int grow = __builtin_amdgcn_readfirstlane(s*DIM + hd*HEAD_D + d);
            const float* wr = qkvw + grow*DIM;
            float acc = qkvb[grow];
            #pragma unroll 8
            for (int c = 0; c < DIM; ++c)
                acc = fmaf(xn[lane*XP+c], wr[c], acc);
            float* dst = (s==0) ? qh : ((s==1) ? kh : vh);
            dst[lane*QP + d] = acc;
        }
        __syncthreads();

        float qr[16];
        #pragma unroll
        for (int d = 0; d < 16; ++d) qr[d] = qh[r*QP+d];
        float scr[16];
        int myrid = srid[r];
        #pragma unroll
        for (int jj = 0; jj < 16; ++jj) {
            int colx = g*16 + jj;
            float a = 0.f;
            #pragma unroll
            for (int d = 0; d < 16; ++d) a = fmaf(qr[d], kh[colx*QP+d], a);
            int cti = colx >> 3, ctj = colx & 7;
            int rel = (rti - cti + 7)*15 + (rtj - ctj + 7);
            float b = rpb[rel*HEADS + hd];
            float m = (srid[colx]==myrid) ? 0.f : -100.f;
            scr[jj] = a*0.25f + b + m;
        }
        float mx = scr[0];
        #pragma unroll
        for (int jj = 1; jj < 16; ++jj) mx = fmaxf(mx, scr[jj]);
        mx = fmaxf(mx, __shfl_xor(mx,1));
        mx = fmaxf(mx, __shfl_xor(mx,2));
        float sum = 0.f;
        #pragma unroll
        for (int jj = 0; jj < 16; ++jj) { scr[jj] = __expf(scr[jj]-mx); sum += scr[jj]; }
        sum += __shfl_xor(sum,1);
        sum += __shfl_xor(sum,2);
        float inv = 1.f/sum;
        #pragma unroll
        for (int d = 0; d < 16; ++d) {
            float a = 0.f;
            #pragma unroll
            for (int jj = 0; jj < 16; ++jj) a = fmaf(scr[jj], vh[(g*16+jj)*QP+d], a);
            a += __shfl_xor(a,1);
            a += __shfl_xor(a,2);
            if (g == 0) ao[r*XP + hd*HEAD_D + d] = a*inv;
        }
        __syncthreads();
    }

    for (int it = 0; it < 24; ++it) {
        int c = __builtin_amdgcn_readfirstlane(it*4 + wv);
        const float* wr = projw + c*DIM;
        float acc = projb[c];
        #pragma unroll 8
        for (int k = 0; k < DIM; ++k)
            acc = fmaf(ao[lane*XP+k], wr[k], acc);
        int p2 = spos[lane];
        float shc = x[c*HWSZ + p2];
        out[c*HWSZ + p2] = shc + acc;
    }
}

__global__ __launch_bounds__(256) void mlp_mfma(
    float* __restrict__ io,
    const float* __restrict__ n2w, const float* __restrict__ n2b,
    const short* __restrict__ w1b, const float* __restrict__ f1b,
    const short* __restrict__ w2b, const float* __restrict__ f2b)
{
    __shared__ short lnbuf[64*BFP];
    __shared__ __align__(16) char ubuf[64*XP*4];
    float* lnf = (float*)ubuf;
    short* hbc = (short*)ubuf;

    const int tid  = threadIdx.x;
    const int base = blockIdx.x * 64;

    for (int idx = tid; idx < 64*DIM; idx += 256) {
        int c = idx >> 6, t = idx & 63;
        lnf[t*XP + c] = io[c*HWSZ + base + t];
    }
    __syncthreads();
    {
        int t = tid >> 2, q = tid & 3;
        float xv[24], s1 = 0.f, s2 = 0.f;
        #pragma unroll
        for (int i = 0; i < 24; ++i) {
            float v = lnf[t*XP + q*24 + i]; xv[i] = v; s1 += v; s2 += v*v;
        }
        s1 += __shfl_xor(s1,1); s2 += __shfl_xor(s2,1);
        s1 += __shfl_xor(s1,2); s2 += __shfl_xor(s2,2);
        float mu = s1*(1.f/96.f);
        float rs = rsqrtf(s2*(1.f/96.f) - mu*mu + EPSV);
        #pragma unroll
        for (int i = 0; i < 24; ++i) {
            int c = q*24 + i;
            lnbuf[t*BFP + c] = (short)f2bf((xv[i]-mu)*rs*n2w[c] + n2b[c]);
        }
    }
    __syncthreads();

    const int l = tid & 63, wv = tid >> 6;
    const int mrow = wv*16;
    const int col = l & 15, kq = l >> 4;

    s8v a1[3];
    #pragma unroll
    for (int kb = 0; kb < 3; ++kb)
        a1[kb] = *(const s8v*)&lnbuf[(mrow+col)*BFP + kb*32 + kq*8];

    f4v acc2[6];
    #pragma unroll
    for (int n = 0; n < 6; ++n) acc2[n] = (f4v){0.f,0.f,0.f,0.f};

    for (int ch = 0; ch < 4; ++ch) {
        #pragma unroll
        for (int nt = 0; nt < 6; ++nt) {
            int n0 = ch*96 + nt*16;
            f4v acc = (f4v){0.f,0.f,0.f,0.f};
            #pragma unroll
            for (int kb = 0; kb < 3; ++kb) {
                s8v b = *(const s8v*)&w1b[(n0+col)*96 + kb*32 + kq*8];
                acc = __builtin_amdgcn_mfma_f32_16x16x32_bf16(a1[kb], b, acc, 0, 0, 0);
            }
            float bias = f1b[n0+col];
            #pragma unroll
            for (int i = 0; i < 4; ++i) {
                float g = fast_gelu(acc[i] + bias);
                hbc[(mrow + kq*4 + i)*BFP + nt*16 + col] = (short)f2bf(g);
            }
        }
        __threadfence_block();
        s8v a2[3];
        #pragma unroll
        for (int kb = 0; kb < 3; ++kb)
            a2[kb] = *(const s8v*)&hbc[(mrow+col)*BFP + kb*32 + kq*8];
        #pragma unroll
        for (int nt = 0; nt < 6; ++nt) {
            #pragma unroll
            for (int kb = 0; kb < 3; ++kb) {
                s8v b = *(const s8v*)&w2b[(nt*16+col)*MLP_H + ch*96 + kb*32 + kq*8];
                acc2[nt] = __builtin_amdgcn_mfma_f32_16x16x32_bf16(a2[kb], b, acc2[nt], 0, 0, 0);
            }
        }
        __threadfence_block();
    }

    #pragma unroll
    for (int nt = 0; nt < 6; ++nt) {
        int c = nt*16 + col;
        float bias = f2b[c];
        #pragma unroll
        for (int i = 0; i < 4; ++i) {
            int t = mrow + kq*4 + i;
            float* p = &io[c*HWSZ + base + t];
            *p = *p + acc2[nt][i] + bias;
        }
    }
}

__global__ __launch_bounds__(256) void conv_w(
    const float* __restrict__ f1w, const float* __restrict__ f2w,
    short* __restrict__ ws)
{
    int i = blockIdx.x*256 + threadIdx.x;
    if (i < 36864)      ws[i] = (short)f2bf(f1w[i]);
    else if (i < 73728) ws[i] = (short)f2bf(f2w[i-36864]);
}

extern "C" void kernel_launch(void* const* d_in, const int* in_sizes, int n_in,
                              void* d_out, int out_size, void* d_ws, size_t ws_size,
                              hipStream_t stream) {
    const float* x     = (const float*)d_in[0];
    const float* n1w   = (const float*)d_in[1];
    const float* n1b   = (const float*)d_in[2];
    const float* qkvw  = (const float*)d_in[3];
    const float* qkvb  = (const float*)d_in[4];
    const float* rpb   = (const float*)d_in[5];
    const float* projw = (const float*)d_in[6];
    const float* projb = (const float*)d_in[7];
    const float* n2w   = (const float*)d_in[8];
    const float* n2b   = (const float*)d_in[9];
    const float* f1w   = (const float*)d_in[10];
    const float* f1b   = (const float*)d_in[11];
    const float* f2w   = (const float*)d_in[12];
    const float* f2b   = (const float*)d_in[13];
    float* out = (float*)d_out;

    if (ws_size >= (size_t)WS_FULL * sizeof(short)) {
        short* wsb = (short*)d_ws;
        hipLaunchKernelGGL(conv_all, dim3(204), dim3(256), 0, stream,
                           qkvw, projw, f1w, f2w, rpb, wsb);
        hipLaunchKernelGGL(fused_kernel, dim3(4096), dim3(256), 0, stream,
                           x, n1w, n1b, qkvb, projb, n2w, n2b, f1b, f2b,
                           wsb + OFF_QKV, wsb + OFF_PROJ,
                           wsb + OFF_W1, wsb + OFF_W2, wsb + OFF_BIAS, out);
    } else {
        short* wsb = (short*)d_ws;
        hipLaunchKernelGGL(attn_kernel, dim3(4096), dim3(256), 0, stream,
                           x, n1w, n1b, qkvw, qkvb, rpb, projw, projb, out);
        hipLaunchKernelGGL(conv_w, dim3(288), dim3(256), 0, stream, f1w, f2w, wsb);
        hipLaunchKernelGGL(mlp_mfma, dim3(4096), dim3(256), 0, stream,
                           out, n2w, n2b, wsb, f1b, wsb + 36864, f2b);
    }
}

// Round 6
// 373.449 us; speedup vs baseline: 1.4584x; 1.4584x over previous
//
#include <hip/hip_runtime.h>
#include <math.h>

#define WINSZ  8
#define SHIFTV 4
#define DIM    96
#define HEADS  6
#define HEAD_D 16
#define MLP_H  384
#define HH     512
#define WWID   512
#define HWSZ   (HH*WWID)
#define NTOK   64
#define EPSV   1e-5f
#define XP     97
#define QP     17
#define BFP    120

#define L2E    1.44269504088896f
#define QSC    0.360673760222f   /* 0.25 * log2(e) */

// ws layout (in shorts)
#define OFF_W1   0        /* 36864: fc1 bf16 */
#define OFF_W2   36864    /* 36864: fc2 bf16 */
#define OFF_QKV  73728    /* 27648: qkv_w bf16 */
#define OFF_PROJ 101376   /*  9216: proj_w bf16 */
#define OFF_BIAS 110592   /* 98304: bias+mask table bf16 [4][6][64][64], pre-scaled by log2e */
#define WS_FULL  208896
#define WS_MLP   73728

// LDS pitches
#define QKP 104   /* shorts, qb/kb2/lnb2/hid rows (16B-aligned b128) */
#define VTP 72    /* shorts, vT rows */
#define X1P 97    /* floats, x1 transpose rows */
#define WBP 104   /* shorts, staged weight rows (208 B padded) */

// LDS map (53248 B total -> 3 blocks/CU):
//  phase A: qb@0 (13312) | kb2@13312 (13312) | vT@26624 (13824, ends 40448)
//  post-B2: wbufA@13312 (19968, 96-row chunk) | wbufB@33280 (19968, ends 53248)
//           lnb2/hid@0 over qb; x1 stays in regs
//  post-MLP: x1f@13312 ([64][97] f32 = 24832) over dead wbufs
#define WBA_OFF 13312
#define WBB_OFF 33280
#define SMEM_SZ 53248

typedef __attribute__((ext_vector_type(2))) short  s2v;
typedef __attribute__((ext_vector_type(4))) short  s4v;
typedef __attribute__((ext_vector_type(8))) short  s8v;
typedef __attribute__((ext_vector_type(4))) float  f4v;
typedef __attribute__((ext_vector_type(4))) unsigned short u4v;

__device__ __forceinline__ unsigned short f2bf(float v) {
    union { float f; unsigned u; } c; c.f = v;
    unsigned r = c.u + 0x7fffu + ((c.u >> 16) & 1u);
    return (unsigned short)(r >> 16);
}
__device__ __forceinline__ float bf2f(unsigned short u) {
    union { unsigned u; float f; } c; c.u = ((unsigned)u) << 16; return c.f;
}
// packed f32x2 -> bf16x2 (RNE), 1 VALU instead of 6
__device__ __forceinline__ unsigned pk2(float a, float b) {
    unsigned r;
    asm("v_cvt_pk_bf16_f32 %0, %1, %2" : "=v"(r) : "v"(a), "v"(b));
    return r;
}
__device__ __forceinline__ s4v pk4(f4v v) {
    union { unsigned u[2]; s4v s; } o;
    o.u[0] = pk2(v[0], v[1]);
    o.u[1] = pk2(v[2], v[3]);
    return o.s;
}
__device__ __forceinline__ float fexp2(float x) {
#if __has_builtin(__builtin_amdgcn_exp2f)
    return __builtin_amdgcn_exp2f(x);
#else
    return exp2f(x);
#endif
}
__device__ __forceinline__ unsigned long long shfl64(unsigned long long v, int src) {
    union { unsigned long long q; int i[2]; } c; c.q = v;
    c.i[0] = __shfl(c.i[0], src);
    c.i[1] = __shfl(c.i[1], src);
    return c.q;
}
// tanh-form gelu in exp2 domain.
__device__ __forceinline__ float fast_gelu(float h) {
    float h2 = h*h;
    float u  = fmaf(0.044715f, h2, 1.0f);
    float e  = fexp2(-2.3022082f * h * u);   /* -1.5957691*log2e */
    return h * __builtin_amdgcn_rcpf(1.0f + e);
}

// async 16B global->LDS (direct-to-shared DMA; no VGPR data round-trip).
__device__ __forceinline__ void gld_lds16(const void* g, void* l) {
    __builtin_amdgcn_global_load_lds(
        (const __attribute__((address_space(1))) unsigned*)(g),
        (__attribute__((address_space(3))) unsigned*)(l),
        16, 0, 0);
}

// Stage a 96-row x 192B weight chunk (row stride stride_b in global) into
// LDS at wb with 208B padded pitch. 1248 x 16B transfers, fully coalesced.
__device__ __forceinline__ void stage96(const char* gb, int stride_b,
                                        char* wb, int tid) {
    #pragma unroll
    for (int k = 0; k < 5; ++k) {
        int idx = tid + k*256;
        if (k < 4 || idx < 1248) {
            int r   = idx / 13;          // padded row (13 chunks of 16B each)
            int rem = idx - r*13;        // chunk within padded row
            const char* src = (rem < 12) ? (gb + r*stride_b + rem*16) : gb;
            char* dst = wb + ((tid & ~63) + k*256)*16;   // wave-uniform base
            gld_lds16(src, dst);
        }
    }
}

// chunk n of the MLP weight stream: {fc1[ch], fc2[ch]} x 4 ch (8 chunks)
__device__ __forceinline__ void stage_chunk8(const char* w1B, const char* w2B,
                                             int n, char* dst, int tid) {
    int ch = n >> 1;
    if (n & 1) stage96(w2B + ch*192, 768, dst, tid);         // fc2[ch]: 96 rows, k-slice
    else       stage96(w1B + ch*96*192, 192, dst, tid);      // fc1[ch]: 96 rows full
}

// ---------------------------------------------------------------------------
// conv_all: weights fp32->bf16 + rel-pos-bias/mask table (pre-scaled by
// log2e for the exp2-domain softmax) into ws.
// ---------------------------------------------------------------------------
__global__ __launch_bounds__(256) void conv_all(
    const float* __restrict__ qkvw, const float* __restrict__ projw,
    const float* __restrict__ f1w,  const float* __restrict__ f2w,
    const float* __restrict__ rpb,  short* __restrict__ ws)
{
    int i = (blockIdx.x*256 + threadIdx.x)*4;
    if (i < 110592) {
        const float* src; int off;
        if (i < 36864)       { src = f1w;  off = i;          }
        else if (i < 73728)  { src = f2w;  off = i - 36864;  }
        else if (i < 101376) { src = qkvw; off = i - 73728;  }
        else                 { src = projw; off = i - 101376; }
        f4v v = *(const f4v*)&src[off];
        s4v o;
        #pragma unroll
        for (int j = 0; j < 4; ++j) o[j] = (short)f2bf(v[j]);
        *(s4v*)&ws[i] = o;
    } else if (i < WS_FULL) {
        int idx = i - 110592;
        int tb = idx / 24576;
        int rm = idx - tb*24576;
        int hd = rm >> 12;
        int rc = rm & 4095;
        int r = rc >> 6, c0 = rc & 63;
        int rti = r>>3, rtj = r&7;
        int bh = tb>>1, bw = tb&1;
        int rhr = bh ? (rti<4?1:2) : 0;
        int rwr = bw ? (rtj<4?1:2) : 0;
        s4v o;
        #pragma unroll
        for (int j = 0; j < 4; ++j) {
            int c = c0 + j;
            int cti = c>>3, ctj = c&7;
            int rel = (rti-cti+7)*15 + (rtj-ctj+7);
            float b = rpb[rel*HEADS + hd];
            int rhc = bh ? (cti<4?1:2) : 0;
            int rwc = bw ? (ctj<4?1:2) : 0;
            if (rhr != rhc || rwr != rwc) b -= 100.f;
            o[j] = (short)f2bf(b * L2E);
        }
        *(s4v*)&ws[OFF_BIAS + idx] = o;
    }
}

// ---------------------------------------------------------------------------
// fused_kernel: one block per window. LN1(in-reg) -> QKV -> attention
// (no-max exp2 softmax; out in-place over Q) -> B2 -> [stage fc1[0],fc2[0]]
// -> proj (x1 in regs) -> LN2(in-reg) -> MLP with 96-ROW double-buffered LDS
// weight chunks (8 stages, full-phase lead each; was 16 x 48-row with
// sub-phase lead) -> residual -> store.
// ---------------------------------------------------------------------------
__global__ __launch_bounds__(256,3) void fused_kernel(
    const float* __restrict__ x,
    const float* __restrict__ n1w, const float* __restrict__ n1b,
    const float* __restrict__ qkvb, const float* __restrict__ projb,
    const float* __restrict__ n2w, const float* __restrict__ n2b,
    const float* __restrict__ f1b, const float* __restrict__ f2b,
    const short* __restrict__ wqkv, const short* __restrict__ wproj,
    const short* __restrict__ w1b, const short* __restrict__ w2b,
    const short* __restrict__ btab,
    float* __restrict__ out)
{
    __shared__ __align__(16) char smem[SMEM_SZ];
    short* qb   = (short*)smem;              // [64][104]; aob/lnb2/hid overlay
    short* kb2  = (short*)(smem + 13312);    // [64][104]
    short* vT   = (short*)(smem + 26624);    // [96][72] (ends 40448)
    short* aob  = qb;
    short* lnb2 = qb;
    short* hid  = qb;
    short* wbA  = (short*)(smem + WBA_OFF);  // [96][104] staged chunk A
    short* wbB  = (short*)(smem + WBB_OFF);  // [96][104] staged chunk B
    float* x1f  = (float*)(smem + WBA_OFF);  // [64][97] f32, post-MLP only

    const int tid  = threadIdx.x;
    const int wv   = tid >> 6, lane = tid & 63;
    const int col  = lane & 15, kq = lane >> 4;
    const int trow = wv*16 + col;
    const int mrow = wv*16;

    // ---- block -> window swizzle (4 w-adjacent windows per XCD slot) ----
    int bid = blockIdx.x;
    int wl = (bid & 7)*512 + ((bid >> 5) << 2) + ((bid >> 3) & 3);
    const int wi = wl >> 6, wj = wl & 63;

    // this thread's token position (token = trow, wave-private)
    const int ti = trow>>3, tj = trow&7;
    const int hpos = (wi*8 + ti + SHIFTV) & (HH-1);
    const int wpos = (wj*8 + tj + SHIFTV) & (WWID-1);
    const int p = hpos*WWID + wpos;

    // ---- LN1 fully in registers ----
    s8v bfr[3];
    {
        float v[24], s1 = 0.f, s2 = 0.f;
        #pragma unroll
        for (int kb = 0; kb < 3; ++kb)
            #pragma unroll
            for (int j = 0; j < 8; ++j) {
                float vv = x[(kb*32 + kq*8 + j)*HWSZ + p];
                v[kb*8+j] = vv; s1 += vv; s2 += vv*vv;
            }
        s1 += __shfl_xor(s1, 16); s2 += __shfl_xor(s2, 16);
        s1 += __shfl_xor(s1, 32); s2 += __shfl_xor(s2, 32);
        float mu = s1*(1.f/96.f);
        float rs = rsqrtf(s2*(1.f/96.f) - mu*mu + EPSV);
        #pragma unroll
        for (int kb = 0; kb < 3; ++kb) {
            f4v wA = *(const f4v*)&n1w[kb*32 + kq*8];
            f4v wB = *(const f4v*)&n1w[kb*32 + kq*8 + 4];
            f4v bA = *(const f4v*)&n1b[kb*32 + kq*8];
            f4v bB = *(const f4v*)&n1b[kb*32 + kq*8 + 4];
            float a[8];
            #pragma unroll
            for (int j = 0; j < 4; ++j) {
                a[j]   = (v[kb*8+j]  -mu)*rs*wA[j] + bA[j];
                a[4+j] = (v[kb*8+4+j]-mu)*rs*wB[j] + bB[j];
            }
            union { unsigned u[4]; s8v s; } o;
            #pragma unroll
            for (int j = 0; j < 4; ++j) o.u[j] = pk2(a[2*j], a[2*j+1]);
            bfr[kb] = o.s;
        }
    }

    // ---- hoist shortcut reads (consumed in proj) ----
    float shc[24];
    #pragma unroll
    for (int mt = 0; mt < 6; ++mt)
        #pragma unroll
        for (int i = 0; i < 4; ++i)
            shc[mt*4+i] = x[(mt*16 + kq*4 + i)*HWSZ + p];

    const s8v zfrag = {0,0,0,0,0,0,0,0};

    // ---- QKV: C^T = W_qkv @ LN^T, weight frags batched 9-at-a-time ----
    {
        #pragma unroll
        for (int g = 0; g < 6; ++g) {
            s8v aw[9];
            #pragma unroll
            for (int m = 0; m < 3; ++m)
                #pragma unroll
                for (int kb = 0; kb < 3; ++kb)
                    aw[m*3+kb] = *(const s8v*)&wqkv[((g*3+m)*16+col)*96 + kb*32 + kq*8];
            #pragma unroll
            for (int m = 0; m < 3; ++m) {
                int mt = g*3 + m;
                f4v acc = {0.f,0.f,0.f,0.f};
                #pragma unroll
                for (int kb = 0; kb < 3; ++kb)
                    acc = __builtin_amdgcn_mfma_f32_16x16x32_bf16(aw[m*3+kb], bfr[kb], acc, 0,0,0);
                int od0 = mt*16 + kq*4;
                f4v bia = *(const f4v*)&qkvb[od0];
                if (mt < 6) {
                    f4v t;
                    #pragma unroll
                    for (int i = 0; i < 4; ++i) t[i] = (acc[i]+bia[i])*QSC;
                    *(s4v*)&qb[trow*QKP + od0] = pk4(t);
                } else if (mt < 12) {
                    f4v t;
                    #pragma unroll
                    for (int i = 0; i < 4; ++i) t[i] = acc[i]+bia[i];
                    *(s4v*)&kb2[trow*QKP + od0 - 96] = pk4(t);
                } else {
                    int d0 = od0 - 192;
                    f4v t;
                    #pragma unroll
                    for (int i = 0; i < 4; ++i) t[i] = acc[i]+bia[i];
                    s4v o = pk4(t);
                    #pragma unroll
                    for (int i = 0; i < 4; ++i)
                        vT[(d0+i)*VTP + trow] = o[i];
                }
            }
        }
    }
    __syncthreads();   // B1: k/v (cross-wave) ready

    // ---- heads: S^T = K @ Q^T (log2 domain), no-max exp2 softmax, PV via
    // register shuffles. Bias rows rotate-prefetched one head ahead. ----
    const int tb = ((wi==63)?2:0) | ((wj==63)?1:0);
    u4v bt[4];
    {
        const short* gb = btab + ((tb*6+0)<<12) + (trow<<6);
        #pragma unroll
        for (int mt = 0; mt < 4; ++mt) bt[mt] = *(const u4v*)&gb[mt*16 + kq*4];
    }
    for (int hd = 0; hd < 6; ++hd) {
        u4v btn[4];
        if (hd < 5) {
            const short* gb = btab + ((tb*6+hd+1)<<12) + (trow<<6);
            #pragma unroll
            for (int mt = 0; mt < 4; ++mt) btn[mt] = *(const u4v*)&gb[mt*16 + kq*4];
        }
        s8v bq = zfrag;
        if (kq < 2) bq = *(const s8v*)&qb[trow*QKP + hd*16 + kq*8];
        f4v st[4];
        #pragma unroll
        for (int mt = 0; mt < 4; ++mt) {
            s8v a = zfrag;
            if (kq < 2) a = *(const s8v*)&kb2[(mt*16+col)*QKP + hd*16 + kq*8];
            f4v z = {0.f,0.f,0.f,0.f};
            st[mt] = __builtin_amdgcn_mfma_f32_16x16x32_bf16(a, bq, z, 0,0,0);
        }
        float pe[16];
        #pragma unroll
        for (int mt = 0; mt < 4; ++mt)
            #pragma unroll
            for (int i = 0; i < 4; ++i)
                pe[mt*4+i] = fexp2(st[mt][i] + bf2f(bt[mt][i]));
        float s8r[8];
        #pragma unroll
        for (int j = 0; j < 8; ++j) s8r[j] = pe[2*j] + pe[2*j+1];
        #pragma unroll
        for (int j = 0; j < 4; ++j) s8r[j] += s8r[j+4];
        float sum = (s8r[0]+s8r[2]) + (s8r[1]+s8r[3]);
        sum += __shfl_xor(sum, 16);
        sum += __shfl_xor(sum, 32);
        unsigned long long p64[4];
        #pragma unroll
        for (int mt = 0; mt < 4; ++mt) {
            union { unsigned u[2]; unsigned long long q; } pq;
            pq.u[0] = pk2(pe[mt*4+0], pe[mt*4+1]);
            pq.u[1] = pk2(pe[mt*4+2], pe[mt*4+3]);
            p64[mt] = pq.q;
        }
        const int s0 = col + ((kq & 1) << 5);
        const int sel = kq >> 1;
        f4v g = {0.f,0.f,0.f,0.f};
        #pragma unroll
        for (int c = 0; c < 2; ++c) {
            unsigned long long t0 = shfl64(p64[2*c],   s0);
            unsigned long long t1 = shfl64(p64[2*c+1], s0);
            unsigned long long lo = sel ? t1 : t0;
            unsigned long long u0 = shfl64(p64[2*c],   s0+16);
            unsigned long long u1 = shfl64(p64[2*c+1], s0+16);
            unsigned long long hi = sel ? u1 : u0;
            union { unsigned long long q[2]; s8v v; } bb;
            bb.q[0] = lo; bb.q[1] = hi;
            s8v a = *(const s8v*)&vT[(hd*16+col)*VTP + c*32 + kq*8];
            g = __builtin_amdgcn_mfma_f32_16x16x32_bf16(a, bb.v, g, 0,0,0);
        }
        float linv = __builtin_amdgcn_rcpf(sum);
        f4v gl;
        #pragma unroll
        for (int i = 0; i < 4; ++i) gl[i] = g[i]*linv;
        *(s4v*)&aob[trow*QKP + hd*16 + kq*4] = pk4(gl);
        #pragma unroll
        for (int mt = 0; mt < 4; ++mt) bt[mt] = btn[mt];
    }
    __syncthreads();   // B2: all waves done with kb2/vT (wbufs overwrite next)

    // ---- prefetch first two 96-row chunks (fc1[0], fc2[0]); their latency
    // hides under proj + LN2 (full ~2.5k-cy lead). ----
    stage_chunk8((const char*)w1b, (const char*)w2b, 0, (char*)wbA, tid);
    stage_chunk8((const char*)w1b, (const char*)w2b, 1, (char*)wbB, tid);

    // ---- proj: C^T = W_proj @ ao^T ; x1 = shortcut + proj-out in REGS ----
    float x1r[24];
    {
        s8v bfr2[3];
        #pragma unroll
        for (int kb = 0; kb < 3; ++kb)
            bfr2[kb] = *(const s8v*)&aob[trow*QKP + kb*32 + kq*8];
        #pragma unroll
        for (int g = 0; g < 2; ++g) {
            s8v aw[9];
            #pragma unroll
            for (int m = 0; m < 3; ++m)
                #pragma unroll
                for (int kb = 0; kb < 3; ++kb)
                    aw[m*3+kb] = *(const s8v*)&wproj[((g*3+m)*16+col)*96 + kb*32 + kq*8];
            #pragma unroll
            for (int m = 0; m < 3; ++m) {
                int mt = g*3 + m;
                f4v acc = {0.f,0.f,0.f,0.f};
                #pragma unroll
                for (int kb = 0; kb < 3; ++kb)
                    acc = __builtin_amdgcn_mfma_f32_16x16x32_bf16(aw[m*3+kb], bfr2[kb], acc, 0,0,0);
                int c0 = mt*16 + kq*4;
                f4v pb4 = *(const f4v*)&projb[c0];
                #pragma unroll
                for (int i = 0; i < 4; ++i)
                    x1r[mt*4+i] = shc[mt*4+i] + acc[i] + pb4[i];
            }
        }
    }

    // ---- LN2 fully in registers, write bf16 to lnb2 (over qb) ----
    {
        float s1 = 0.f, s2 = 0.f;
        #pragma unroll
        for (int j = 0; j < 24; ++j) { s1 += x1r[j]; s2 += x1r[j]*x1r[j]; }
        s1 += __shfl_xor(s1, 16); s2 += __shfl_xor(s2, 16);
        s1 += __shfl_xor(s1, 32); s2 += __shfl_xor(s2, 32);
        float mu = s1*(1.f/96.f);
        float rs = rsqrtf(s2*(1.f/96.f) - mu*mu + EPSV);
        #pragma unroll
        for (int mt = 0; mt < 6; ++mt) {
            int c0 = mt*16 + kq*4;
            f4v w4 = *(const f4v*)&n2w[c0];
            f4v b4 = *(const f4v*)&n2b[c0];
            f4v t;
            #pragma unroll
            for (int i = 0; i < 4; ++i)
                t[i] = (x1r[mt*4+i]-mu)*rs*w4[i] + b4[i];
            *(s4v*)&lnb2[trow*QKP + c0] = pk4(t);
        }
    }
    __threadfence_block();

    // ---- MLP: 8 phases {fc1[ch], fc2[ch]} with 96-row double buffer.
    // Per phase: compute full matrix (18 MFMA); sync; stage chunk p+2 into
    // the buffer just freed -- a full phase (+barrier) of lead. ----
    s8v a1[3], a2[3];
    #pragma unroll
    for (int kb = 0; kb < 3; ++kb)
        a1[kb] = *(const s8v*)&lnb2[(mrow+col)*QKP + kb*32 + kq*8];

    f4v acc2[6];
    #pragma unroll
    for (int n = 0; n < 6; ++n) acc2[n] = (f4v){0.f,0.f,0.f,0.f};

    __syncthreads();   // chunks 0,1 staged+visible; a1 read before hid writes

    #pragma unroll
    for (int ph = 0; ph < 8; ++ph) {
        const short* wb = (ph & 1) ? wbB : wbA;
        const int ch = ph >> 1;
        if ((ph & 1) == 0) {
            // fc1[ch]: hidden = gelu(a1 @ W1[ch]) -> hid (wave-private rows)
            #pragma unroll
            for (int nl = 0; nl < 6; ++nl) {
                f4v acc = (f4v){0.f,0.f,0.f,0.f};
                #pragma unroll
                for (int kb = 0; kb < 3; ++kb) {
                    s8v b = *(const s8v*)&wb[(nl*16+col)*WBP + kb*32 + kq*8];
                    acc = __builtin_amdgcn_mfma_f32_16x16x32_bf16(a1[kb], b, acc, 0,0,0);
                }
                int cch = nl*16 + col;
                float bias = f1b[ch*96 + cch];
                f4v t;
                #pragma unroll
                for (int i = 0; i < 4; ++i) t[i] = fast_gelu(acc[i]+bias);
                s4v o = pk4(t);
                #pragma unroll
                for (int i = 0; i < 4; ++i)
                    hid[(mrow + kq*4 + i)*QKP + cch] = o[i];
            }
            __threadfence_block();
            #pragma unroll
            for (int kb = 0; kb < 3; ++kb)
                a2[kb] = *(const s8v*)&hid[(mrow+col)*QKP + kb*32 + kq*8];
        } else {
            // fc2[ch]: acc2 += a2 @ W2[:, ch-slice]
            #pragma unroll
            for (int nl = 0; nl < 6; ++nl) {
                #pragma unroll
                for (int kb = 0; kb < 3; ++kb) {
                    s8v b = *(const s8v*)&wb[(nl*16+col)*WBP + kb*32 + kq*8];
                    acc2[nl] = __builtin_amdgcn_mfma_f32_16x16x32_bf16(a2[kb], b, acc2[nl], 0,0,0);
                }
            }
        }
        __syncthreads();            // all waves done with this buffer
        if (ph + 2 < 8)
            stage_chunk8((const char*)w1b, (const char*)w2b, ph+2,
                         (char*)((ph & 1) ? wbB : wbA), tid);
    }
    // final loop barrier also protects wbufs before x1f overwrite

    // ---- residual transpose through freed LDS, then channel-major store ----
    #pragma unroll
    for (int mt = 0; mt < 6; ++mt) {
        #pragma unroll
        for (int i = 0; i < 4; ++i)
            x1f[trow*X1P + mt*16 + kq*4 + i] = x1r[mt*4+i];
    }
    __threadfence_block();
    #pragma unroll
    for (int nt = 0; nt < 6; ++nt) {
        int c = nt*16 + col;
        float bias = f2b[c];
        #pragma unroll
        for (int i = 0; i < 4; ++i) {
            int t = mrow + kq*4 + i;
            x1f[t*X1P + c] += acc2[nt][i] + bias;
        }
    }
    __threadfence_block();
    {
        int tt = mrow + col;
        int tti = tt>>3, ttj = tt&7;
        int pp = ((wi*8 + tti + SHIFTV) & (HH-1))*WWID + ((wj*8 + ttj + SHIFTV) & (WWID-1));
        #pragma unroll
        for (int it = 0; it < 24; ++it) {
            int c = it*4 + kq;
            out[c*HWSZ + pp] = x1f[tt*X1P + c];
        }
    }
}

// ---------------------------------------------------------------------------
// Fallback fp32 attention + bf16 MLP if ws too small.
// ---------------------------------------------------------------------------
__global__ __launch_bounds__(256) void attn_kernel(
    const float* __restrict__ x,
    const float* __restrict__ n1w, const float* __restrict__ n1b,
    const float* __restrict__ qkvw, const float* __restrict__ qkvb,
    const float* __restrict__ rpb,
    const float* __restrict__ projw, const float* __restrict__ projb,
    float* __restrict__ out)
{
    __shared__ float xn[NTOK*XP];
    __shared__ float ao[NTOK*XP];
    __shared__ float qh[NTOK*QP];
    __shared__ float kh[NTOK*QP];
    __shared__ float vh[NTOK*QP];
    __shared__ int   srid[NTOK];
    __shared__ int   spos[NTOK];

    const int tid = threadIdx.x;
    const int blk = blockIdx.x;
    const int wi = blk >> 6, wj = blk & 63;

    {
        int t  = tid >> 2;
        int j4 = tid & 3;
        int ti = t >> 3, tj = t & 7;
        int a = wi*WINSZ + ti;
        int bcol = wj*WINSZ + tj;
        int h = (a + SHIFTV) & (HH-1);
        int w = (bcol + SHIFTV) & (WWID-1);
        int p = h*WWID + w;
        if (j4 == 0) {
            spos[t] = p;
            int rh = (a < HH-WINSZ) ? 0 : (a < HH-SHIFTV ? 1 : 2);
            int rw = (bcol < WWID-WINSZ) ? 0 : (bcol < WWID-SHIFTV ? 1 : 2);
            srid[t] = rh*3 + rw;
        }
        float xv[24];
        float s1 = 0.f, s2 = 0.f;
        int c0 = j4*24;
        #pragma unroll
        for (int i = 0; i < 24; ++i) {
            float v = x[(c0+i)*HWSZ + p];
            xv[i] = v; s1 += v; s2 += v*v;
        }
        s1 += __shfl_xor(s1,1); s2 += __shfl_xor(s2,1);
        s1 += __shfl_xor(s1,2); s2 += __shfl_xor(s2,2);
        float mu  = s1 * (1.f/96.f);
        float var = s2 * (1.f/96.f) - mu*mu;
        float rs  = rsqrtf(var + EPSV);
        #pragma unroll
        for (int i = 0; i < 24; ++i) {
            int c = c0 + i;
            xn[t*XP + c] = (xv[i]-mu)*rs*n1w[c] + n1b[c];
        }
    }
    __syncthreads();

    const int wv   = tid >> 6;
    const int lane = tid & 63;
    const int r    = tid >> 2;
    const int g    = tid & 3;
    const int rti  = r >> 3, rtj = r & 7;

    for (int hd = 0; hd < HEADS; ++hd) {
        for (int it = 0; it < 12; ++it) {
            int ol = it*4 + wv;
            int s = ol >> 4, d = ol & 15;
            int grow = __builtin_amdgcn_readfirstlane(s*DIM + hd*HEAD_D + d);
            const float* wr = qkvw + grow*DIM;
            float acc = qkvb[grow];
            #pragma unroll 8
            for (int c = 0; c < DIM; ++c)
                acc = fmaf(xn[lane*XP+c], wr[c], acc);
            float* dst = (s==0) ? qh : ((s==1) ? kh : vh);
            dst[lane*QP + d] = acc;
        }
        __syncthreads();

        float qr[16];
        #pragma unroll
        for (int d = 0; d < 16; ++d) qr[d] = qh[r*QP+d];
        float scr[16];
        int myrid = srid[r];
        #pragma unroll
        for (int jj = 0; jj < 16; ++jj) {
            int colx = g*16 + jj;
            float a = 0.f;
            #pragma unroll
            for (int d = 0; d < 16; ++d) a = fmaf(qr[d], kh[colx*QP+d], a);
            int cti = colx >> 3, ctj = colx & 7;
            int rel = (rti - cti + 7)*15 + (rtj - ctj + 7);
            float b = rpb[rel*HEADS + hd];
            float m = (srid[colx]==myrid) ? 0.f : -100.f;
            scr[jj] = a*0.25f + b + m;
        }
        float mx = scr[0];
        #pragma unroll
        for (int jj = 1; jj < 16; ++jj) mx = fmaxf(mx, scr[jj]);
        mx = fmaxf(mx, __shfl_xor(mx,1));
        mx = fmaxf(mx, __shfl_xor(mx,2));
        float sum = 0.f;
        #pragma unroll
        for (int jj = 0; jj < 16; ++jj) { scr[jj] = __expf(scr[jj]-mx); sum += scr[jj]; }
        sum += __shfl_xor(sum,1);
        sum += __shfl_xor(sum,2);
        float inv = 1.f/sum;
        #pragma unroll
        for (int d = 0; d < 16; ++d) {
            float a = 0.f;
            #pragma unroll
            for (int jj = 0; jj < 16; ++jj) a = fmaf(scr[jj], vh[(g*16+jj)*QP+d], a);
            a += __shfl_xor(a,1);
            a += __shfl_xor(a,2);
            if (g == 0) ao[r*XP + hd*HEAD_D + d] = a*inv;
        }
        __syncthreads();
    }

    for (int it = 0; it < 24; ++it) {
        int c = __builtin_amdgcn_readfirstlane(it*4 + wv);
        const float* wr = projw + c*DIM;
        float acc = projb[c];
        #pragma unroll 8
        for (int k = 0; k < DIM; ++k)
            acc = fmaf(ao[lane*XP+k], wr[k], acc);
        int p2 = spos[lane];
        float shc = x[c*HWSZ + p2];
        out[c*HWSZ + p2] = shc + acc;
    }
}

__global__ __launch_bounds__(256) void mlp_mfma(
    float* __restrict__ io,
    const float* __restrict__ n2w, const float* __restrict__ n2b,
    const short* __restrict__ w1b, const float* __restrict__ f1b,
    const short* __restrict__ w2b, const float* __restrict__ f2b)
{
    __shared__ short lnbuf[64*BFP];
    __shared__ __align__(16) char ubuf[64*XP*4];
    float* lnf = (float*)ubuf;
    short* hbc = (short*)ubuf;

    const int tid  = threadIdx.x;
    const int base = blockIdx.x * 64;

    for (int idx = tid; idx < 64*DIM; idx += 256) {
        int c = idx >> 6, t = idx & 63;
        lnf[t*XP + c] = io[c*HWSZ + base + t];
    }
    __syncthreads();
    {
        int t = tid >> 2, q = tid & 3;
        float xv[24], s1 = 0.f, s2 = 0.f;
        #pragma unroll
        for (int i = 0; i < 24; ++i) {
            float v = lnf[t*XP + q*24 + i]; xv[i] = v; s1 += v; s2 += v*v;
        }
        s1 += __shfl_xor(s1,1); s2 += __shfl_xor(s2,1);
        s1 += __shfl_xor(s1,2); s2 += __shfl_xor(s2,2);
        float mu = s1*(1.f/96.f);
        float rs = rsqrtf(s2*(1.f/96.f) - mu*mu + EPSV);
        #pragma unroll
        for (int i = 0; i < 24; ++i) {
            int c = q*24 + i;
            lnbuf[t*BFP + c] = (short)f2bf((xv[i]-mu)*rs*n2w[c] + n2b[c]);
        }
    }
    __syncthreads();

    const int l = tid & 63, wv = tid >> 6;
    const int mrow = wv*16;
    const int col = l & 15, kq = l >> 4;

    s8v a1[3];
    #pragma unroll
    for (int kb = 0; kb < 3; ++kb)
        a1[kb] = *(const s8v*)&lnbuf[(mrow+col)*BFP + kb*32 + kq*8];

    f4v acc2[6];
    #pragma unroll
    for (int n = 0; n < 6; ++n) acc2[n] = (f4v){0.f,0.f,0.f,0.f};

    for (int ch = 0; ch < 4; ++ch) {
        #pragma unroll
        for (int nt = 0; nt < 6; ++nt) {
            int n0 = ch*96 + nt*16;
            f4v acc = (f4v){0.f,0.f,0.f,0.f};
            #pragma unroll
            for (int kb = 0; kb < 3; ++kb) {
                s8v b = *(const s8v*)&w1b[(n0+col)*96 + kb*32 + kq*8];
                acc = __builtin_amdgcn_mfma_f32_16x16x32_bf16(a1[kb], b, acc, 0, 0, 0);
            }
            float bias = f1b[n0+col];
            #pragma unroll
            for (int i = 0; i < 4; ++i) {
                float g = fast_gelu(acc[i] + bias);
                hbc[(mrow + kq*4 + i)*BFP + nt*16 + col] = (short)f2bf(g);
            }
        }
        __threadfence_block();
        s8v a2[3];
        #pragma unroll
        for (int kb = 0; kb < 3; ++kb)
            a2[kb] = *(const s8v*)&hbc[(mrow+col)*BFP + kb*32 + kq*8];
        #pragma unroll
        for (int nt = 0; nt < 6; ++nt) {
            #pragma unroll
            for (int kb = 0; kb < 3; ++kb) {
                s8v b = *(const s8v*)&w2b[(nt*16+col)*MLP_H + ch*96 + kb*32 + kq*8];
                acc2[nt] = __builtin_amdgcn_mfma_f32_16x16x32_bf16(a2[kb], b, acc2[nt], 0, 0, 0);
            }
        }
        __threadfence_block();
    }

    #pragma unroll
    for (int nt = 0; nt < 6; ++nt) {
        int c = nt*16 + col;
        float bias = f2b[c];
        #pragma unroll
        for (int i = 0; i < 4; ++i) {
            int t = mrow + kq*4 + i;
            float* p = &io[c*HWSZ + base + t];
            *p = *p + acc2[nt][i] + bias;
        }
    }
}

__global__ __launch_bounds__(256) void conv_w(
    const float* __restrict__ f1w, const float* __restrict__ f2w,
    short* __restrict__ ws)
{
    int i = blockIdx.x*256 + threadIdx.x;
    if (i < 36864)      ws[i] = (short)f2bf(f1w[i]);
    else if (i < 73728) ws[i] = (short)f2bf(f2w[i-36864]);
}

extern "C" void kernel_launch(void* const* d_in, const int* in_sizes, int n_in,
                              void* d_out, int out_size, void* d_ws, size_t ws_size,
                              hipStream_t stream) {
    const float* x     = (const float*)d_in[0];
    const float* n1w   = (const float*)d_in[1];
    const float* n1b   = (const float*)d_in[2];
    const float* qkvw  = (const float*)d_in[3];
    const float* qkvb  = (const float*)d_in[4];
    const float* rpb   = (const float*)d_in[5];
    const float* projw = (const float*)d_in[6];
    const float* projb = (const float*)d_in[7];
    const float* n2w   = (const float*)d_in[8];
    const float* n2b   = (const float*)d_in[9];
    const float* f1w   = (const float*)d_in[10];
    const float* f1b   = (const float*)d_in[11];
    const float* f2w   = (const float*)d_in[12];
    const float* f2b   = (const float*)d_in[13];
    float* out = (float*)d_out;

    if (ws_size >= (size_t)WS_FULL * sizeof(short)) {
        short* wsb = (short*)d_ws;
        hipLaunchKernelGGL(conv_all, dim3(204), dim3(256), 0, stream,
                           qkvw, projw, f1w, f2w, rpb, wsb);
        hipLaunchKernelGGL(fused_kernel, dim3(4096), dim3(256), 0, stream,
                           x, n1w, n1b, qkvb, projb, n2w, n2b, f1b, f2b,
                           wsb + OFF_QKV, wsb + OFF_PROJ,
                           wsb + OFF_W1, wsb + OFF_W2, wsb + OFF_BIAS, out);
    } else {
        short* wsb = (short*)d_ws;
        hipLaunchKernelGGL(attn_kernel, dim3(4096), dim3(256), 0, stream,
                           x, n1w, n1b, qkvw, qkvb, rpb, projw, projb, out);
        hipLaunchKernelGGL(conv_w, dim3(288), dim3(256), 0, stream, f1w, f2w, wsb);
        hipLaunchKernelGGL(mlp_mfma, dim3(4096), dim3(256), 0, stream,
                           out, n2w, n2b, wsb, f1b, wsb + 36864, f2b);
    }
}